// Round 11
// baseline (252.741 us; speedup 1.0000x reference)
//
#include <hip/hip_runtime.h>

#define BB 64
#define TT 512
#define NN 48
#define PP 16

typedef float f4 __attribute__((ext_vector_type(4)));
typedef short s8v __attribute__((ext_vector_type(8)));
typedef int i4v __attribute__((ext_vector_type(4)));

#define LN2 0.6931471805599453f

// Manual RNE bf16 pack. DO NOT replace: hand-written v_cvt_pk_bf16_f32 asm
// (round 6) produced NaN; __float22bfloat162_rn intrinsic (round 8) caused a
// device abort. This sequence is the only verified-good pack in this kernel.
__device__ __forceinline__ unsigned f2bf_bits(float x) {
    unsigned u = __builtin_bit_cast(unsigned, x);
    return (u + 0x7fffu + ((u >> 16) & 1u)) >> 16;
}
__device__ __forceinline__ int pk_bf16(float a, float b) {
    return (int)(f2bf_bits(a) | (f2bf_bits(b) << 16));
}
__device__ __forceinline__ float wsum(float v) {
#pragma unroll
    for (int k = 32; k >= 1; k >>= 1) v += __shfl_xor(v, k, 64);
    return v;
}

#define MFMA(A_, B_, C_) __builtin_amdgcn_mfma_f32_16x16x32_bf16(A_, B_, C_, 0, 0, 0)

// Opaque async load: 3x16B per lane into fixed vregs. The compiler cannot sink
// these (asm volatile) and inserts NO waitcnt for them — we control draining.
// NOTE: this manual vmcnt discipline is only sound in a SPILL-FREE kernel —
// scratch spill stores/reloads also bump vmcnt and corrupt the ring accounting.
// Hence launch_bounds must leave the full 512-VGPR budget (see crf_fused).
__device__ __forceinline__ void aload3(const float* q, float4& a, float4& b, float4& c) {
    asm volatile(
        "global_load_dwordx4 %0, %3, off\n\t"
        "global_load_dwordx4 %1, %3, off offset:64\n\t"
        "global_load_dwordx4 %2, %3, off offset:128"
        : "=v"(a), "=v"(b), "=v"(c)
        : "v"(q)
        : "memory");
}
// wait until at most N vector loads outstanding; block scheduler motion across.
#define WAITVM(N)                                                                   \
    do {                                                                            \
        __builtin_amdgcn_s_waitcnt((((N) & 0xF)) | ((((N) >> 4) & 0x3) << 14) |     \
                                   0x0F70);                                         \
        __builtin_amdgcn_sched_barrier(0);                                          \
    } while (0)

#define RESCALE(CNT)                                                         \
    do {                                                                     \
        float Sx = ((D0[0] + D0[1]) + (D0[2] + D0[3])) +                     \
                   ((D1[0] + D1[1]) + (D1[2] + D1[3])) +                     \
                   ((D2[0] + D2[1]) + (D2[2] + D2[3]));                      \
        Sx += __shfl_xor(Sx, 16, 64);                                        \
        Sx += __shfl_xor(Sx, 32, 64);                                        \
        int e_ = (__builtin_bit_cast(int, Sx) >> 23) - 127;                  \
        float scl_ = __builtin_bit_cast(float, (127 - e_) << 23);            \
        CNT += e_;                                                           \
        D0 *= scl_; D1 *= scl_; D2 *= scl_;                                  \
    } while (0)

#define EMMUL(E0, E1, E2)                                                    \
    do {                                                                     \
        D0[0] *= __expf(E0.x); D0[1] *= __expf(E0.y);                        \
        D0[2] *= __expf(E0.z); D0[3] *= __expf(E0.w);                        \
        D1[0] *= __expf(E1.x); D1[1] *= __expf(E1.y);                        \
        D1[2] *= __expf(E1.z); D1[3] *= __expf(E1.w);                        \
        D2[0] *= __expf(E2.x); D2[1] *= __expf(E2.y);                        \
        D2[2] *= __expf(E2.z); D2[3] *= __expf(E2.w);                        \
    } while (0)

#define REPACK_B()                                                           \
    do {                                                                     \
        i4v nb0 = {pk_bf16(D0[0], D0[1]), pk_bf16(D0[2], D0[3]),             \
                   pk_bf16(D1[0], D1[1]), pk_bf16(D1[2], D1[3])};            \
        i4v nb1 = {pk_bf16(D2[0], D2[1]), pk_bf16(D2[2], D2[3]), 0, 0};      \
        B0 = __builtin_bit_cast(s8v, nb0);                                   \
        B1 = __builtin_bit_cast(s8v, nb1);                                   \
    } while (0)

#define DO_MFMA6()                                                           \
    do {                                                                     \
        D0 = MFMA(A[0][1], B1, Z); D0 = MFMA(A[0][0], B0, D0);               \
        D1 = MFMA(A[1][1], B1, Z); D1 = MFMA(A[1][0], B0, D1);               \
        D2 = MFMA(A[2][1], B1, Z); D2 = MFMA(A[2][0], B0, D2);               \
    } while (0)

// One chain step on ring slot dd. Expanded in chain(); binds local names
// (r, j, nsteps, issue, A, B0, B1, D0..D2, Cexp, Z) at the expansion site.
// Numerics identical to the original per-step body.
#define CHAIN_STEP(dd)                                                       \
    {                                                                        \
        float4 e0 = r[dd][0], e1 = r[dd][1], e2 = r[dd][2];                  \
        if (!BWD) {                                                          \
            DO_MFMA6();                                                      \
            EMMUL(e0, e1, e2);                                               \
            if (j == nsteps) goto done;                                      \
            if ((j & (RP - 1)) == 0) RESCALE(Cexp);                          \
            REPACK_B();                                                      \
        } else {                                                             \
            EMMUL(e0, e1, e2);                                               \
            REPACK_B();                                                      \
            DO_MFMA6();                                                      \
            if (j == nsteps) goto done;                                      \
            if ((j & (RP - 1)) == 0) RESCALE(Cexp);                          \
        }                                                                    \
        issue(dd, j + DEPTH);                                                \
        ++j;                                                                 \
    }

// ---------------------------------------------------------------------------
// Shared chain core. 16 seqs/wave (seq = lane&15), σ-permuted K axis so the D
// fragment repacks directly into the next B fragment. Emissions come through a
// DEPTH-deep asm-load ring (3 dwordx4/step), drained with manual vmcnt waits.
// FWD: alpha' = exp(em) ⊙ (Eᵀ alpha), rows 1..nsteps (B must be pre-inited).
// BWD: beta'  = E·(beta ⊙ exp(em)),  rows hi, hi-1, ... (nsteps rows), D=1 init.
// Even DEPTH (T chains): TWO steps per WAITVM — the fence count halves and the
// compiler gets a 2-step window to hoist step j+1's exp()s (load-dependent
// only) under step j's MFMA latency. Steady state: 24 in flight → wait to
// 3*(DEPTH-2)=18 → slots d,d+1 landed → 2 bodies → reissue 3+3. Odd DEPTH
// (LR, DEPTH=5) keeps the original verified per-step loop unchanged.
// ---------------------------------------------------------------------------
template <int RP, int DEPTH, bool BWD>
__device__ __forceinline__ void chain(const float* __restrict__ p0, int estride,
                                      int nsteps, int hi, const s8v (&A)[3][2],
                                      s8v& B0, s8v& B1, f4& D0, f4& D1, f4& D2,
                                      int& Cexp) {
    const f4 Z = {0.f, 0.f, 0.f, 0.f};
    float4 r[DEPTH][3];
    auto issue = [&](int d, int j) {
        int rw = BWD ? (hi - (j - 1)) : j;
        if (BWD) { if (rw < 0) rw = 0; } else { if (rw > nsteps) rw = nsteps; }
        aload3(p0 + (size_t)rw * (size_t)estride, r[d][0], r[d][1], r[d][2]);
    };
#pragma unroll
    for (int d = 0; d < DEPTH; ++d) issue(d, 1 + d);

    int j = 1;
    if constexpr ((DEPTH & 1) == 0) {
        for (;;) {
#pragma unroll
            for (int d = 0; d < DEPTH; d += 2) {
                WAITVM(3 * (DEPTH - 2));  // two oldest slots (d, d+1) landed
                CHAIN_STEP(d)
                CHAIN_STEP(d + 1)
            }
        }
    } else {
        for (;;) {
#pragma unroll
            for (int d = 0; d < DEPTH; ++d) {
                WAITVM(3 * (DEPTH - 1));  // oldest 3 loads (slot d) have landed
                CHAIN_STEP(d)
            }
        }
    }
done:
    WAITVM(0);  // drain ring: slots' vregs may be reused by later code
}

__device__ __forceinline__ void initB(const float* __restrict__ p0, s8v& B0, s8v& B1) {
    float4 ua = *(const float4*)(p0);
    float4 ub = *(const float4*)(p0 + 16);
    float4 uc = *(const float4*)(p0 + 32);
    i4v b0i = {pk_bf16(__expf(ua.x), __expf(ua.y)), pk_bf16(__expf(ua.z), __expf(ua.w)),
               pk_bf16(__expf(ub.x), __expf(ub.y)), pk_bf16(__expf(ub.z), __expf(ub.w))};
    i4v b1i = {pk_bf16(__expf(uc.x), __expf(uc.y)), pk_bf16(__expf(uc.z), __expf(uc.w)), 0, 0};
    B0 = __builtin_bit_cast(s8v, b0i);
    B1 = __builtin_bit_cast(s8v, b1i);
}

// L/R denominator: fwd chain + final logsum.
template <int RP, int DEPTH>
__device__ __forceinline__ float den16a(const float* __restrict__ p0, int estride,
                                        int steps, const s8v (&A)[3][2]) {
    const f4 Zi = {0.f, 0.f, 0.f, 0.f};
    f4 D0 = Zi, D1 = Zi, D2 = Zi;
    s8v B0, B1;
    int Cexp = 0;
    initB(p0, B0, B1);
    chain<RP, DEPTH, false>(p0, estride, steps, 0, A, B0, B1, D0, D1, D2, Cexp);
    float S = ((D0[0] + D0[1]) + (D0[2] + D0[3])) +
              ((D1[0] + D1[1]) + (D1[2] + D1[3])) +
              ((D2[0] + D2[1]) + (D2[2] + D2[3]));
    S += __shfl_xor(S, 16, 64);
    S += __shfl_xor(S, 32, 64);
    return __logf(S) + (float)Cexp * LN2;
}

__device__ __forceinline__ float den0(const float* __restrict__ p0) {
    float4 ua = *(const float4*)(p0);
    float4 ub = *(const float4*)(p0 + 16);
    float4 uc = *(const float4*)(p0 + 32);
    float S = (__expf(ua.x) + __expf(ua.y) + __expf(ua.z) + __expf(ua.w)) +
              (__expf(ub.x) + __expf(ub.y) + __expf(ub.z) + __expf(ub.w)) +
              (__expf(uc.x) + __expf(uc.y) + __expf(uc.z) + __expf(uc.w));
    S += __shfl_xor(S, 16, 64);
    S += __shfl_xor(S, 32, 64);
    return __logf(S);
}

// A-frags fwd: A[m][k] = exp(trans[σ(k)][t*16+m])  (Eᵀ·u)
__device__ __forceinline__ void build_A_fwd(const float* __restrict__ st, s8v (&A)[3][2]) {
    int lane = threadIdx.x & 63, m = lane & 15, quad = lane >> 4;
#pragma unroll
    for (int t = 0; t < 3; ++t) {
        int col = t * 16 + m;
        i4v v0 = {pk_bf16(__expf(st[(quad * 4 + 0) * NN + col]), __expf(st[(quad * 4 + 1) * NN + col])),
                  pk_bf16(__expf(st[(quad * 4 + 2) * NN + col]), __expf(st[(quad * 4 + 3) * NN + col])),
                  pk_bf16(__expf(st[(16 + quad * 4 + 0) * NN + col]), __expf(st[(16 + quad * 4 + 1) * NN + col])),
                  pk_bf16(__expf(st[(16 + quad * 4 + 2) * NN + col]), __expf(st[(16 + quad * 4 + 3) * NN + col]))};
        i4v v1 = {pk_bf16(__expf(st[(32 + quad * 4 + 0) * NN + col]), __expf(st[(32 + quad * 4 + 1) * NN + col])),
                  pk_bf16(__expf(st[(32 + quad * 4 + 2) * NN + col]), __expf(st[(32 + quad * 4 + 3) * NN + col])),
                  0, 0};
        A[t][0] = __builtin_bit_cast(s8v, v0);
        A[t][1] = __builtin_bit_cast(s8v, v1);
    }
}

// A-frags bwd: A[m][k] = exp(trans[t*16+m][σ(k)])  (E·x)
__device__ __forceinline__ void build_A_bwd(const float* __restrict__ st, s8v (&A)[3][2]) {
    int lane = threadIdx.x & 63, m = lane & 15, quad = lane >> 4;
#pragma unroll
    for (int t = 0; t < 3; ++t) {
        const float* row = st + (t * 16 + m) * NN;
        i4v v0 = {pk_bf16(__expf(row[quad * 4 + 0]), __expf(row[quad * 4 + 1])),
                  pk_bf16(__expf(row[quad * 4 + 2]), __expf(row[quad * 4 + 3])),
                  pk_bf16(__expf(row[16 + quad * 4 + 0]), __expf(row[16 + quad * 4 + 1])),
                  pk_bf16(__expf(row[16 + quad * 4 + 2]), __expf(row[16 + quad * 4 + 3]))};
        i4v v1 = {pk_bf16(__expf(row[32 + quad * 4 + 0]), __expf(row[32 + quad * 4 + 1])),
                  pk_bf16(__expf(row[32 + quad * 4 + 2]), __expf(row[32 + quad * 4 + 3])),
                  0, 0};
        A[t][0] = __builtin_bit_cast(s8v, v0);
        A[t][1] = __builtin_bit_cast(s8v, v1);
    }
}

__device__ __forceinline__ void dumpD(float* __restrict__ dst, int* __restrict__ cdst,
                                      int g, f4 D0, f4 D1, f4 D2, int Cexp) {
    int lane = threadIdx.x & 63, seq = lane & 15, quad = lane >> 4;
    float* b = dst + (size_t)(g * 16 + seq) * 48 + quad * 4;
#pragma unroll
    for (int r = 0; r < 4; ++r) {
        b[0 * 16 + r] = D0[r];
        b[1 * 16 + r] = D1[r];
        b[2 * 16 + r] = D2[r];
    }
    if (quad == 0) cdst[g * 16 + seq] = Cexp;
}

__global__ void zero_out(float* out) {
    if (threadIdx.x < 3) out[threadIdx.x] = 0.f;
}

#define WS_BETA (64 * 16 * 48)
#define WS_C (2 * 64 * 16 * 48)

// ---------------------------------------------------------------------------
// crf_fused: 4480 blocks x 64 thr. bid<128: pyramid-T halves (longest waves,
// dispatched first); else LR work. Fusion overlaps the latency-bound halves
// (round-4/9 verified: ~131 µs dispatch, total ~248-250 µs, VGPR=128).
// T path runs at s_setprio(1): the T chains are the kernel's serial critical
// path; priority keeps them progressing at near-solo rate while LR waves
// (latency-tolerant, 4352 of them) share the CUs. Pure scheduler hint.
// __launch_bounds__(64,1): full 512-VGPR budget — REQUIRED (spill ops bump
// vmcnt and corrupt the asm-ring accounting; (64,3) caused the round-3 abort).
// pk_bf16 must remain the manual sequence (rounds 6/8 regressions).
// ---------------------------------------------------------------------------
__global__ __launch_bounds__(64, 1) void crf_fused(const float* __restrict__ logits,
                                                   const float* __restrict__ transT,
                                                   const float* __restrict__ transL,
                                                   const float* __restrict__ transR,
                                                   const int* __restrict__ tags,
                                                   float* __restrict__ out,
                                                   float* __restrict__ ws) {
    __shared__ float st[NN * NN];
    const int tid = threadIdx.x, bid = blockIdx.x;
    const int lane = tid & 63;
    const int quad = lane >> 4, seq = lane & 15;
    const int SPN = BB * TT * NN;

    if (bid < 128) {
        // ---- former crf_T: pyramid-T chains, fwd half (dir=0) / bwd half ----
        __builtin_amdgcn_s_setprio(1);
        for (int i = tid; i < NN * NN; i += 64) st[i] = transT[i];
        __syncthreads();

        const int dir = bid >> 6, g = bid & 63;
        const int p = g >> 2, b0 = (g & 3) * 16;
        const int steps = (TT - 1) - p;
        const int m = steps >> 1, nb = steps - m;
        const float* p0 = logits + (size_t)(p * BB + b0 + seq) * (TT * NN) + quad * 4;

        s8v A[3][2];
        const f4 Zi = {0.f, 0.f, 0.f, 0.f};
        f4 D0 = Zi, D1 = Zi, D2 = Zi;
        s8v B0, B1;
        int Cexp = 0;
        int* cf = (int*)(ws + WS_C);
        if (dir == 0) {
            build_A_fwd(st, A);
            initB(p0, B0, B1);
            chain<4, 8, false>(p0, NN, m, 0, A, B0, B1, D0, D1, D2, Cexp);
            dumpD(ws, cf, g, D0, D1, D2, Cexp);
        } else {
            build_A_bwd(st, A);
            D0 = f4{1.f, 1.f, 1.f, 1.f}; D1 = D0; D2 = D0;
            chain<4, 8, true>(p0, NN, nb, steps, A, B0, B1, D0, D1, D2, Cexp);
            dumpD(ws + WS_BETA, cf + 1024, g, D0, D1, D2, Cexp);
        }
        return;
    }

    // ---- former crf_LR ----
    const int lb = bid - 128;

    const float* tr;
    if (lb < 1984) tr = transL;
    else if (lb < 3968) tr = transR;
    else if (lb < 4032) tr = transL;
    else if (lb < 4096) tr = transR;
    else tr = transT;
    for (int i = tid; i < NN * NN; i += 64) st[i] = tr[i];
    __syncthreads();

    float contrib = 0.f;
    int oi;
    if (lb < 3968) {
        const int isL = lb < 1984;
        const int i = isL ? lb : lb - 1984;
        const int tb = i >> 6, b = i & 63;
        const int t0 = (isL ? 0 : 16) + tb * 16;
        oi = isL ? 1 : 2;
        const int estride = isL ? SPN : SPN - NN;
        s8v A[3][2];
        build_A_fwd(st, A);
        const float* p0 = logits + (size_t)(b * TT + t0 + seq) * NN + quad * 4;
        float ld = den16a<8, 5>(p0, estride, PP - 1, A);
        int sq = lane >> 2, pc = lane & 3;
        int tq = t0 + sq;
        float sc = 0.f;
        if (isL) {
            for (int p2 = pc; p2 < PP; p2 += 4) {
                int ix = (p2 * BB + b) * TT + tq;
                int tg = tags[ix];
                sc += logits[(size_t)ix * NN + tg];
                if (p2 >= 1) sc += st[tags[ix - BB * TT] * NN + tg];
            }
        } else {
            for (int p2 = pc; p2 < PP; p2 += 4) {
                int ix = (p2 * BB + b) * TT + (tq - p2);
                int tg = tags[ix];
                sc += logits[(size_t)ix * NN + tg];
                if (p2 >= 1) sc += st[tags[ix - BB * TT + 1] * NN + tg];
            }
        }
        contrib = ((quad == 0) ? ld : 0.f) - sc;
    } else if (lb < 4096) {
        const int isL = lb < 4032;
        const int i = isL ? lb - 3968 : lb - 4032;
        const int t = isL ? 496 + (i >> 2) : (i >> 2);
        const int b0 = (i & 3) * 16;
        oi = isL ? 1 : 2;
        const int Lh = isL ? (TT - t) : (t + 1);
        const int steps = Lh - 1;
        const int estride = isL ? SPN : SPN - NN;
        s8v A[3][2];
        build_A_fwd(st, A);
        const float* p0 = logits + (size_t)(b0 + seq) * (TT * NN) + t * NN + quad * 4;
        float ld = (steps > 0) ? den16a<8, 5>(p0, estride, steps, A) : den0(p0);
        float sc = 0.f;
        int sq = lane >> 2, pc = lane & 3;
        int bq = b0 + sq;
        if (isL) {
            for (int p2 = pc; p2 < Lh; p2 += 4) {
                int ix = (p2 * BB + bq) * TT + t;
                int tg = tags[ix];
                sc += logits[(size_t)ix * NN + tg];
                if (p2 >= 1) sc += st[tags[ix - BB * TT] * NN + tg];
            }
        } else {
            for (int p2 = pc; p2 < Lh; p2 += 4) {
                int ix = (p2 * BB + bq) * TT + (t - p2);
                int tg = tags[ix];
                sc += logits[(size_t)ix * NN + tg];
                if (p2 >= 1) sc += st[tags[ix - BB * TT + 1] * NN + tg];
            }
        }
        contrib = ((quad == 0) ? ld : 0.f) - sc;
    } else {
        oi = 0;
        int q = lb - 4096;
        int g = q >> 2, phase = q & 3;
        int p = g >> 2, b0 = (g & 3) * 16;
        int Ls = TT - p;
        int sq = lane >> 2;
        int t0 = phase * 4 + (lane & 3);
        const float* lgs = logits + (size_t)(p * BB + b0 + sq) * (TT * NN);
        const int* tgs = tags + (size_t)(p * BB + b0 + sq) * TT;
        float sc = 0.f;
        for (int t = t0; t < Ls; t += 16) {
            int tg = tgs[t];
            float e = lgs[t * NN + tg];
            float tsc = (t >= 1) ? st[tgs[t - 1] * NN + tg] : 0.f;
            sc += e + tsc;
        }
        contrib = -sc;
    }

    contrib = wsum(contrib);
    if (lane == 0) atomicAdd(&out[oi], contrib);
}

// Combine T halves: out[0] += Σ_idx [ log(Σ_s alpha*beta) + ln2*(cf+cb) ]
__global__ __launch_bounds__(256) void t_combine(const float* __restrict__ ws,
                                                 float* __restrict__ out) {
    const int idx = blockIdx.x * 256 + threadIdx.x;  // 0..1023
    const float* ap = ws + (size_t)idx * 48;
    const float* bp = ws + WS_BETA + (size_t)idx * 48;
    const int* cf = (const int*)(ws + WS_C);
    const int* cb = cf + 1024;
    float Zv = 0.f;
#pragma unroll
    for (int s = 0; s < 48; ++s) Zv += ap[s] * bp[s];
    float acc = __logf(Zv) + LN2 * (float)(cf[idx] + cb[idx]);
    acc = wsum(acc);
    if ((threadIdx.x & 63) == 0) atomicAdd(&out[0], acc);
}

extern "C" void kernel_launch(void* const* d_in, const int* in_sizes, int n_in,
                              void* d_out, int out_size, void* d_ws, size_t ws_size,
                              hipStream_t stream) {
    const float* logits = (const float*)d_in[0];
    const float* trans_T = (const float*)d_in[1];
    const float* trans_L = (const float*)d_in[2];
    const float* trans_R = (const float*)d_in[3];
    const int* tags = (const int*)d_in[4];
    float* out = (float*)d_out;
    float* ws = (float*)d_ws;

    hipLaunchKernelGGL(zero_out, dim3(1), dim3(64), 0, stream, out);
    hipLaunchKernelGGL(crf_fused, dim3(4480), dim3(64), 0, stream,
                       logits, trans_T, trans_L, trans_R, tags, out, ws);
    hipLaunchKernelGGL(t_combine, dim3(4), dim3(256), 0, stream, ws, out);
}

// Round 21
// 251.355 us; speedup vs baseline: 1.0055x; 1.0055x over previous
//
#include <hip/hip_runtime.h>

#define BB 64
#define TT 512
#define NN 48
#define PP 16

typedef float f4 __attribute__((ext_vector_type(4)));
typedef short s8v __attribute__((ext_vector_type(8)));
typedef int i4v __attribute__((ext_vector_type(4)));

#define LN2 0.6931471805599453f

// Manual RNE bf16 pack. DO NOT replace: hand-written v_cvt_pk_bf16_f32 asm
// (round 6) produced NaN; __float22bfloat162_rn intrinsic (round 8) caused a
// device abort. This sequence is the only verified-good pack in this kernel.
__device__ __forceinline__ unsigned f2bf_bits(float x) {
    unsigned u = __builtin_bit_cast(unsigned, x);
    return (u + 0x7fffu + ((u >> 16) & 1u)) >> 16;
}
__device__ __forceinline__ int pk_bf16(float a, float b) {
    return (int)(f2bf_bits(a) | (f2bf_bits(b) << 16));
}
__device__ __forceinline__ float wsum(float v) {
#pragma unroll
    for (int k = 32; k >= 1; k >>= 1) v += __shfl_xor(v, k, 64);
    return v;
}

#define MFMA(A_, B_, C_) __builtin_amdgcn_mfma_f32_16x16x32_bf16(A_, B_, C_, 0, 0, 0)

// Opaque async load: 3x16B per lane into fixed vregs. The compiler cannot sink
// these (asm volatile) and inserts NO waitcnt for them — we control draining.
// NOTE: this manual vmcnt discipline is only sound in a SPILL-FREE kernel —
// scratch spill stores/reloads also bump vmcnt and corrupt the ring accounting.
// DEPTH=8 (96 ring VGPRs) is the empirical size limit: DEPTH=12 and DEPTH=16
// both fragmented the allocator into scratch spill → abort (rounds 16/20).
__device__ __forceinline__ void aload3(const float* q, float4& a, float4& b, float4& c) {
    asm volatile(
        "global_load_dwordx4 %0, %3, off\n\t"
        "global_load_dwordx4 %1, %3, off offset:64\n\t"
        "global_load_dwordx4 %2, %3, off offset:128"
        : "=v"(a), "=v"(b), "=v"(c)
        : "v"(q)
        : "memory");
}
// wait until at most N vector loads outstanding; block scheduler motion across.
#define WAITVM(N)                                                                   \
    do {                                                                            \
        __builtin_amdgcn_s_waitcnt((((N) & 0xF)) | ((((N) >> 4) & 0x3) << 14) |     \
                                   0x0F70);                                         \
        __builtin_amdgcn_sched_barrier(0);                                          \
    } while (0)

#define RESCALE(CNT)                                                         \
    do {                                                                     \
        float Sx = ((D0[0] + D0[1]) + (D0[2] + D0[3])) +                     \
                   ((D1[0] + D1[1]) + (D1[2] + D1[3])) +                     \
                   ((D2[0] + D2[1]) + (D2[2] + D2[3]));                      \
        Sx += __shfl_xor(Sx, 16, 64);                                        \
        Sx += __shfl_xor(Sx, 32, 64);                                        \
        int e_ = (__builtin_bit_cast(int, Sx) >> 23) - 127;                  \
        float scl_ = __builtin_bit_cast(float, (127 - e_) << 23);            \
        CNT += e_;                                                           \
        D0 *= scl_; D1 *= scl_; D2 *= scl_;                                  \
    } while (0)

#define EMMUL(E0, E1, E2)                                                    \
    do {                                                                     \
        D0[0] *= __expf(E0.x); D0[1] *= __expf(E0.y);                        \
        D0[2] *= __expf(E0.z); D0[3] *= __expf(E0.w);                        \
        D1[0] *= __expf(E1.x); D1[1] *= __expf(E1.y);                        \
        D1[2] *= __expf(E1.z); D1[3] *= __expf(E1.w);                        \
        D2[0] *= __expf(E2.x); D2[1] *= __expf(E2.y);                        \
        D2[2] *= __expf(E2.z); D2[3] *= __expf(E2.w);                        \
    } while (0)

#define REPACK_B()                                                           \
    do {                                                                     \
        i4v nb0 = {pk_bf16(D0[0], D0[1]), pk_bf16(D0[2], D0[3]),             \
                   pk_bf16(D1[0], D1[1]), pk_bf16(D1[2], D1[3])};            \
        i4v nb1 = {pk_bf16(D2[0], D2[1]), pk_bf16(D2[2], D2[3]), 0, 0};      \
        B0 = __builtin_bit_cast(s8v, nb0);                                   \
        B1 = __builtin_bit_cast(s8v, nb1);                                   \
    } while (0)

#define DO_MFMA6()                                                           \
    do {                                                                     \
        D0 = MFMA(A[0][1], B1, Z); D0 = MFMA(A[0][0], B0, D0);               \
        D1 = MFMA(A[1][1], B1, Z); D1 = MFMA(A[1][0], B0, D1);               \
        D2 = MFMA(A[2][1], B1, Z); D2 = MFMA(A[2][0], B0, D2);               \
    } while (0)

// ---------------------------------------------------------------------------
// Shared chain core. 16 seqs/wave (seq = lane&15), σ-permuted K axis so the D
// fragment repacks directly into the next B fragment. Emissions come through a
// DEPTH-deep asm-load ring (3 dwordx4/step), drained with manual vmcnt waits.
// FWD: alpha' = exp(em) ⊙ (Eᵀ alpha), rows 1..nsteps (B must be pre-inited).
// BWD: beta'  = E·(beta ⊙ exp(em)),  rows hi, hi-1, ... (nsteps rows), D=1 init.
// DEPTH=8 is the verified working maximum (12/16 spill → abort, rounds 16/20).
// Round-11's paired-drain (wait 6 loads/2 steps) regressed +18% — keep
// per-step wait-for-3. This is the round-9 verified kernel (247.8-250 µs).
// ---------------------------------------------------------------------------
template <int RP, int DEPTH, bool BWD>
__device__ __forceinline__ void chain(const float* __restrict__ p0, int estride,
                                      int nsteps, int hi, const s8v (&A)[3][2],
                                      s8v& B0, s8v& B1, f4& D0, f4& D1, f4& D2,
                                      int& Cexp) {
    const f4 Z = {0.f, 0.f, 0.f, 0.f};
    float4 r[DEPTH][3];
    auto issue = [&](int d, int j) {
        int rw = BWD ? (hi - (j - 1)) : j;
        if (BWD) { if (rw < 0) rw = 0; } else { if (rw > nsteps) rw = nsteps; }
        aload3(p0 + (size_t)rw * (size_t)estride, r[d][0], r[d][1], r[d][2]);
    };
#pragma unroll
    for (int d = 0; d < DEPTH; ++d) issue(d, 1 + d);

    int j = 1;
    for (;;) {
#pragma unroll
        for (int d = 0; d < DEPTH; ++d) {
            WAITVM(3 * (DEPTH - 1));  // oldest 3 loads (slot d) have landed
            float4 e0 = r[d][0], e1 = r[d][1], e2 = r[d][2];
            if (!BWD) {
                DO_MFMA6();
                EMMUL(e0, e1, e2);
                if (j == nsteps) goto done;
                if ((j & (RP - 1)) == 0) RESCALE(Cexp);
                REPACK_B();
            } else {
                EMMUL(e0, e1, e2);
                REPACK_B();
                DO_MFMA6();
                if (j == nsteps) goto done;
                if ((j & (RP - 1)) == 0) RESCALE(Cexp);
            }
            issue(d, j + DEPTH);
            ++j;
        }
    }
done:
    WAITVM(0);  // drain ring: slots' vregs may be reused by later code
}

__device__ __forceinline__ void initB(const float* __restrict__ p0, s8v& B0, s8v& B1) {
    float4 ua = *(const float4*)(p0);
    float4 ub = *(const float4*)(p0 + 16);
    float4 uc = *(const float4*)(p0 + 32);
    i4v b0i = {pk_bf16(__expf(ua.x), __expf(ua.y)), pk_bf16(__expf(ua.z), __expf(ua.w)),
               pk_bf16(__expf(ub.x), __expf(ub.y)), pk_bf16(__expf(ub.z), __expf(ub.w))};
    i4v b1i = {pk_bf16(__expf(uc.x), __expf(uc.y)), pk_bf16(__expf(uc.z), __expf(uc.w)), 0, 0};
    B0 = __builtin_bit_cast(s8v, b0i);
    B1 = __builtin_bit_cast(s8v, b1i);
}

// L/R denominator: fwd chain + final logsum.
template <int RP, int DEPTH>
__device__ __forceinline__ float den16a(const float* __restrict__ p0, int estride,
                                        int steps, const s8v (&A)[3][2]) {
    const f4 Zi = {0.f, 0.f, 0.f, 0.f};
    f4 D0 = Zi, D1 = Zi, D2 = Zi;
    s8v B0, B1;
    int Cexp = 0;
    initB(p0, B0, B1);
    chain<RP, DEPTH, false>(p0, estride, steps, 0, A, B0, B1, D0, D1, D2, Cexp);
    float S = ((D0[0] + D0[1]) + (D0[2] + D0[3])) +
              ((D1[0] + D1[1]) + (D1[2] + D1[3])) +
              ((D2[0] + D2[1]) + (D2[2] + D2[3]));
    S += __shfl_xor(S, 16, 64);
    S += __shfl_xor(S, 32, 64);
    return __logf(S) + (float)Cexp * LN2;
}

__device__ __forceinline__ float den0(const float* __restrict__ p0) {
    float4 ua = *(const float4*)(p0);
    float4 ub = *(const float4*)(p0 + 16);
    float4 uc = *(const float4*)(p0 + 32);
    float S = (__expf(ua.x) + __expf(ua.y) + __expf(ua.z) + __expf(ua.w)) +
              (__expf(ub.x) + __expf(ub.y) + __expf(ub.z) + __expf(ub.w)) +
              (__expf(uc.x) + __expf(uc.y) + __expf(uc.z) + __expf(uc.w));
    S += __shfl_xor(S, 16, 64);
    S += __shfl_xor(S, 32, 64);
    return __logf(S);
}

// A-frags fwd: A[m][k] = exp(trans[σ(k)][t*16+m])  (Eᵀ·u)
__device__ __forceinline__ void build_A_fwd(const float* __restrict__ st, s8v (&A)[3][2]) {
    int lane = threadIdx.x & 63, m = lane & 15, quad = lane >> 4;
#pragma unroll
    for (int t = 0; t < 3; ++t) {
        int col = t * 16 + m;
        i4v v0 = {pk_bf16(__expf(st[(quad * 4 + 0) * NN + col]), __expf(st[(quad * 4 + 1) * NN + col])),
                  pk_bf16(__expf(st[(quad * 4 + 2) * NN + col]), __expf(st[(quad * 4 + 3) * NN + col])),
                  pk_bf16(__expf(st[(16 + quad * 4 + 0) * NN + col]), __expf(st[(16 + quad * 4 + 1) * NN + col])),
                  pk_bf16(__expf(st[(16 + quad * 4 + 2) * NN + col]), __expf(st[(16 + quad * 4 + 3) * NN + col]))};
        i4v v1 = {pk_bf16(__expf(st[(32 + quad * 4 + 0) * NN + col]), __expf(st[(32 + quad * 4 + 1) * NN + col])),
                  pk_bf16(__expf(st[(32 + quad * 4 + 2) * NN + col]), __expf(st[(32 + quad * 4 + 3) * NN + col])),
                  0, 0};
        A[t][0] = __builtin_bit_cast(s8v, v0);
        A[t][1] = __builtin_bit_cast(s8v, v1);
    }
}

// A-frags bwd: A[m][k] = exp(trans[t*16+m][σ(k)])  (E·x)
__device__ __forceinline__ void build_A_bwd(const float* __restrict__ st, s8v (&A)[3][2]) {
    int lane = threadIdx.x & 63, m = lane & 15, quad = lane >> 4;
#pragma unroll
    for (int t = 0; t < 3; ++t) {
        const float* row = st + (t * 16 + m) * NN;
        i4v v0 = {pk_bf16(__expf(row[quad * 4 + 0]), __expf(row[quad * 4 + 1])),
                  pk_bf16(__expf(row[quad * 4 + 2]), __expf(row[quad * 4 + 3])),
                  pk_bf16(__expf(row[16 + quad * 4 + 0]), __expf(row[16 + quad * 4 + 1])),
                  pk_bf16(__expf(row[16 + quad * 4 + 2]), __expf(row[16 + quad * 4 + 3]))};
        i4v v1 = {pk_bf16(__expf(row[32 + quad * 4 + 0]), __expf(row[32 + quad * 4 + 1])),
                  pk_bf16(__expf(row[32 + quad * 4 + 2]), __expf(row[32 + quad * 4 + 3])),
                  0, 0};
        A[t][0] = __builtin_bit_cast(s8v, v0);
        A[t][1] = __builtin_bit_cast(s8v, v1);
    }
}

__device__ __forceinline__ void dumpD(float* __restrict__ dst, int* __restrict__ cdst,
                                      int g, f4 D0, f4 D1, f4 D2, int Cexp) {
    int lane = threadIdx.x & 63, seq = lane & 15, quad = lane >> 4;
    float* b = dst + (size_t)(g * 16 + seq) * 48 + quad * 4;
#pragma unroll
    for (int r = 0; r < 4; ++r) {
        b[0 * 16 + r] = D0[r];
        b[1 * 16 + r] = D1[r];
        b[2 * 16 + r] = D2[r];
    }
    if (quad == 0) cdst[g * 16 + seq] = Cexp;
}

__global__ void zero_out(float* out) {
    if (threadIdx.x < 3) out[threadIdx.x] = 0.f;
}

#define WS_BETA (64 * 16 * 48)
#define WS_C (2 * 64 * 16 * 48)

// ---------------------------------------------------------------------------
// crf_fused: 4480 blocks x 64 thr. bid<128: pyramid-T halves (longest waves,
// dispatched first); else LR work. Fusion overlaps the latency-bound halves
// (rounds 4/9 verified: ~131 µs dispatch, total 247.8-250.0 µs).
// FINAL session config. Probed and rejected: pack variants (NaN/abort, r6/r8),
// paired-drain+setprio (+18%, r11), DEPTH 12/16 (ring spill → abort, r16/r20).
// __launch_bounds__(64,1): full 512-VGPR budget — REQUIRED (spill ops bump
// vmcnt and corrupt the asm-ring accounting; (64,3) caused the round-3 abort).
// ---------------------------------------------------------------------------
__global__ __launch_bounds__(64, 1) void crf_fused(const float* __restrict__ logits,
                                                   const float* __restrict__ transT,
                                                   const float* __restrict__ transL,
                                                   const float* __restrict__ transR,
                                                   const int* __restrict__ tags,
                                                   float* __restrict__ out,
                                                   float* __restrict__ ws) {
    __shared__ float st[NN * NN];
    const int tid = threadIdx.x, bid = blockIdx.x;
    const int lane = tid & 63;
    const int quad = lane >> 4, seq = lane & 15;
    const int SPN = BB * TT * NN;

    if (bid < 128) {
        // ---- former crf_T: pyramid-T chains, fwd half (dir=0) / bwd half ----
        for (int i = tid; i < NN * NN; i += 64) st[i] = transT[i];
        __syncthreads();

        const int dir = bid >> 6, g = bid & 63;
        const int p = g >> 2, b0 = (g & 3) * 16;
        const int steps = (TT - 1) - p;
        const int m = steps >> 1, nb = steps - m;
        const float* p0 = logits + (size_t)(p * BB + b0 + seq) * (TT * NN) + quad * 4;

        s8v A[3][2];
        const f4 Zi = {0.f, 0.f, 0.f, 0.f};
        f4 D0 = Zi, D1 = Zi, D2 = Zi;
        s8v B0, B1;
        int Cexp = 0;
        int* cf = (int*)(ws + WS_C);
        if (dir == 0) {
            build_A_fwd(st, A);
            initB(p0, B0, B1);
            chain<4, 8, false>(p0, NN, m, 0, A, B0, B1, D0, D1, D2, Cexp);
            dumpD(ws, cf, g, D0, D1, D2, Cexp);
        } else {
            build_A_bwd(st, A);
            D0 = f4{1.f, 1.f, 1.f, 1.f}; D1 = D0; D2 = D0;
            chain<4, 8, true>(p0, NN, nb, steps, A, B0, B1, D0, D1, D2, Cexp);
            dumpD(ws + WS_BETA, cf + 1024, g, D0, D1, D2, Cexp);
        }
        return;
    }

    // ---- former crf_LR ----
    const int lb = bid - 128;

    const float* tr;
    if (lb < 1984) tr = transL;
    else if (lb < 3968) tr = transR;
    else if (lb < 4032) tr = transL;
    else if (lb < 4096) tr = transR;
    else tr = transT;
    for (int i = tid; i < NN * NN; i += 64) st[i] = tr[i];
    __syncthreads();

    float contrib = 0.f;
    int oi;
    if (lb < 3968) {
        const int isL = lb < 1984;
        const int i = isL ? lb : lb - 1984;
        const int tb = i >> 6, b = i & 63;
        const int t0 = (isL ? 0 : 16) + tb * 16;
        oi = isL ? 1 : 2;
        const int estride = isL ? SPN : SPN - NN;
        s8v A[3][2];
        build_A_fwd(st, A);
        const float* p0 = logits + (size_t)(b * TT + t0 + seq) * NN + quad * 4;
        float ld = den16a<8, 5>(p0, estride, PP - 1, A);
        int sq = lane >> 2, pc = lane & 3;
        int tq = t0 + sq;
        float sc = 0.f;
        if (isL) {
            for (int p2 = pc; p2 < PP; p2 += 4) {
                int ix = (p2 * BB + b) * TT + tq;
                int tg = tags[ix];
                sc += logits[(size_t)ix * NN + tg];
                if (p2 >= 1) sc += st[tags[ix - BB * TT] * NN + tg];
            }
        } else {
            for (int p2 = pc; p2 < PP; p2 += 4) {
                int ix = (p2 * BB + b) * TT + (tq - p2);
                int tg = tags[ix];
                sc += logits[(size_t)ix * NN + tg];
                if (p2 >= 1) sc += st[tags[ix - BB * TT + 1] * NN + tg];
            }
        }
        contrib = ((quad == 0) ? ld : 0.f) - sc;
    } else if (lb < 4096) {
        const int isL = lb < 4032;
        const int i = isL ? lb - 3968 : lb - 4032;
        const int t = isL ? 496 + (i >> 2) : (i >> 2);
        const int b0 = (i & 3) * 16;
        oi = isL ? 1 : 2;
        const int Lh = isL ? (TT - t) : (t + 1);
        const int steps = Lh - 1;
        const int estride = isL ? SPN : SPN - NN;
        s8v A[3][2];
        build_A_fwd(st, A);
        const float* p0 = logits + (size_t)(b0 + seq) * (TT * NN) + t * NN + quad * 4;
        float ld = (steps > 0) ? den16a<8, 5>(p0, estride, steps, A) : den0(p0);
        float sc = 0.f;
        int sq = lane >> 2, pc = lane & 3;
        int bq = b0 + sq;
        if (isL) {
            for (int p2 = pc; p2 < Lh; p2 += 4) {
                int ix = (p2 * BB + bq) * TT + t;
                int tg = tags[ix];
                sc += logits[(size_t)ix * NN + tg];
                if (p2 >= 1) sc += st[tags[ix - BB * TT] * NN + tg];
            }
        } else {
            for (int p2 = pc; p2 < Lh; p2 += 4) {
                int ix = (p2 * BB + bq) * TT + (t - p2);
                int tg = tags[ix];
                sc += logits[(size_t)ix * NN + tg];
                if (p2 >= 1) sc += st[tags[ix - BB * TT + 1] * NN + tg];
            }
        }
        contrib = ((quad == 0) ? ld : 0.f) - sc;
    } else {
        oi = 0;
        int q = lb - 4096;
        int g = q >> 2, phase = q & 3;
        int p = g >> 2, b0 = (g & 3) * 16;
        int Ls = TT - p;
        int sq = lane >> 2;
        int t0 = phase * 4 + (lane & 3);
        const float* lgs = logits + (size_t)(p * BB + b0 + sq) * (TT * NN);
        const int* tgs = tags + (size_t)(p * BB + b0 + sq) * TT;
        float sc = 0.f;
        for (int t = t0; t < Ls; t += 16) {
            int tg = tgs[t];
            float e = lgs[t * NN + tg];
            float tsc = (t >= 1) ? st[tgs[t - 1] * NN + tg] : 0.f;
            sc += e + tsc;
        }
        contrib = -sc;
    }

    contrib = wsum(contrib);
    if (lane == 0) atomicAdd(&out[oi], contrib);
}

// Combine T halves: out[0] += Σ_idx [ log(Σ_s alpha*beta) + ln2*(cf+cb) ]
__global__ __launch_bounds__(256) void t_combine(const float* __restrict__ ws,
                                                 float* __restrict__ out) {
    const int idx = blockIdx.x * 256 + threadIdx.x;  // 0..1023
    const float* ap = ws + (size_t)idx * 48;
    const float* bp = ws + WS_BETA + (size_t)idx * 48;
    const int* cf = (const int*)(ws + WS_C);
    const int* cb = cf + 1024;
    float Zv = 0.f;
#pragma unroll
    for (int s = 0; s < 48; ++s) Zv += ap[s] * bp[s];
    float acc = __logf(Zv) + LN2 * (float)(cf[idx] + cb[idx]);
    acc = wsum(acc);
    if ((threadIdx.x & 63) == 0) atomicAdd(&out[0], acc);
}

extern "C" void kernel_launch(void* const* d_in, const int* in_sizes, int n_in,
                              void* d_out, int out_size, void* d_ws, size_t ws_size,
                              hipStream_t stream) {
    const float* logits = (const float*)d_in[0];
    const float* trans_T = (const float*)d_in[1];
    const float* trans_L = (const float*)d_in[2];
    const float* trans_R = (const float*)d_in[3];
    const int* tags = (const int*)d_in[4];
    float* out = (float*)d_out;
    float* ws = (float*)d_ws;

    hipLaunchKernelGGL(zero_out, dim3(1), dim3(64), 0, stream, out);
    hipLaunchKernelGGL(crf_fused, dim3(4480), dim3(64), 0, stream,
                       logits, trans_T, trans_L, trans_R, tags, out, ws);
    hipLaunchKernelGGL(t_combine, dim3(4), dim3(256), 0, stream, ws, out);
}

// Round 22
// 236.227 us; speedup vs baseline: 1.0699x; 1.0640x over previous
//
#include <hip/hip_runtime.h>

#define BB 64
#define TT 512
#define NN 48
#define PP 16

typedef float f4 __attribute__((ext_vector_type(4)));
typedef short s8v __attribute__((ext_vector_type(8)));
typedef int i4v __attribute__((ext_vector_type(4)));

#define LN2 0.6931471805599453f

// Manual RNE bf16 pack. DO NOT replace: hand-written v_cvt_pk_bf16_f32 asm
// (round 6) produced NaN; __float22bfloat162_rn intrinsic (round 8) caused a
// device abort. This sequence is the only verified-good pack in this kernel.
__device__ __forceinline__ unsigned f2bf_bits(float x) {
    unsigned u = __builtin_bit_cast(unsigned, x);
    return (u + 0x7fffu + ((u >> 16) & 1u)) >> 16;
}
__device__ __forceinline__ int pk_bf16(float a, float b) {
    return (int)(f2bf_bits(a) | (f2bf_bits(b) << 16));
}
__device__ __forceinline__ float wsum(float v) {
#pragma unroll
    for (int k = 32; k >= 1; k >>= 1) v += __shfl_xor(v, k, 64);
    return v;
}

#define MFMA(A_, B_, C_) __builtin_amdgcn_mfma_f32_16x16x32_bf16(A_, B_, C_, 0, 0, 0)

// Opaque async load: 3x16B per lane into fixed vregs. The compiler cannot sink
// these (asm volatile) and inserts NO waitcnt for them — we control draining.
// NOTE: this manual vmcnt discipline is only sound in a SPILL-FREE kernel —
// scratch spill stores/reloads also bump vmcnt and corrupt the ring accounting.
// DEPTH=8 (96 ring VGPRs) is the empirical size limit: DEPTH=12 and DEPTH=16
// both fragmented the allocator into scratch spill → abort (rounds 16/20).
__device__ __forceinline__ void aload3(const float* q, float4& a, float4& b, float4& c) {
    asm volatile(
        "global_load_dwordx4 %0, %3, off\n\t"
        "global_load_dwordx4 %1, %3, off offset:64\n\t"
        "global_load_dwordx4 %2, %3, off offset:128"
        : "=v"(a), "=v"(b), "=v"(c)
        : "v"(q)
        : "memory");
}
// wait until at most N vector loads outstanding; block scheduler motion across.
#define WAITVM(N)                                                                   \
    do {                                                                            \
        __builtin_amdgcn_s_waitcnt((((N) & 0xF)) | ((((N) >> 4) & 0x3) << 14) |     \
                                   0x0F70);                                         \
        __builtin_amdgcn_sched_barrier(0);                                          \
    } while (0)

#define RESCALE(CNT)                                                         \
    do {                                                                     \
        float Sx = ((D0[0] + D0[1]) + (D0[2] + D0[3])) +                     \
                   ((D1[0] + D1[1]) + (D1[2] + D1[3])) +                     \
                   ((D2[0] + D2[1]) + (D2[2] + D2[3]));                      \
        Sx += __shfl_xor(Sx, 16, 64);                                        \
        Sx += __shfl_xor(Sx, 32, 64);                                        \
        int e_ = (__builtin_bit_cast(int, Sx) >> 23) - 127;                  \
        float scl_ = __builtin_bit_cast(float, (127 - e_) << 23);            \
        CNT += e_;                                                           \
        D0 *= scl_; D1 *= scl_; D2 *= scl_;                                  \
    } while (0)

#define EMMUL(E0, E1, E2)                                                    \
    do {                                                                     \
        D0[0] *= __expf(E0.x); D0[1] *= __expf(E0.y);                        \
        D0[2] *= __expf(E0.z); D0[3] *= __expf(E0.w);                        \
        D1[0] *= __expf(E1.x); D1[1] *= __expf(E1.y);                        \
        D1[2] *= __expf(E1.z); D1[3] *= __expf(E1.w);                        \
        D2[0] *= __expf(E2.x); D2[1] *= __expf(E2.y);                        \
        D2[2] *= __expf(E2.z); D2[3] *= __expf(E2.w);                        \
    } while (0)

#define REPACK_B()                                                           \
    do {                                                                     \
        i4v nb0 = {pk_bf16(D0[0], D0[1]), pk_bf16(D0[2], D0[3]),             \
                   pk_bf16(D1[0], D1[1]), pk_bf16(D1[2], D1[3])};            \
        i4v nb1 = {pk_bf16(D2[0], D2[1]), pk_bf16(D2[2], D2[3]), 0, 0};      \
        B0 = __builtin_bit_cast(s8v, nb0);                                   \
        B1 = __builtin_bit_cast(s8v, nb1);                                   \
    } while (0)

#define DO_MFMA6()                                                           \
    do {                                                                     \
        D0 = MFMA(A[0][1], B1, Z); D0 = MFMA(A[0][0], B0, D0);               \
        D1 = MFMA(A[1][1], B1, Z); D1 = MFMA(A[1][0], B0, D1);               \
        D2 = MFMA(A[2][1], B1, Z); D2 = MFMA(A[2][0], B0, D2);               \
    } while (0)

// ---------------------------------------------------------------------------
// Shared chain core. 16 seqs/wave (seq = lane&15), σ-permuted K axis so the D
// fragment repacks directly into the next B fragment. Emissions come through a
// DEPTH-deep asm-load ring (3 dwordx4/step), drained with manual vmcnt waits.
// FWD: alpha' = exp(em) ⊙ (Eᵀ alpha), rows 1..nsteps (B must be pre-inited).
// BWD: beta'  = E·(beta ⊙ exp(em)),  rows hi, hi-1, ... (nsteps rows), D=1 init.
// DEPTH=8 is the verified working maximum (12/16 spill → abort, rounds 16/20).
// Round-11's paired-drain (wait 6 loads/2 steps) regressed +18% — keep
// per-step wait-for-3.
// ---------------------------------------------------------------------------
template <int RP, int DEPTH, bool BWD>
__device__ __forceinline__ void chain(const float* __restrict__ p0, int estride,
                                      int nsteps, int hi, const s8v (&A)[3][2],
                                      s8v& B0, s8v& B1, f4& D0, f4& D1, f4& D2,
                                      int& Cexp) {
    const f4 Z = {0.f, 0.f, 0.f, 0.f};
    float4 r[DEPTH][3];
    auto issue = [&](int d, int j) {
        int rw = BWD ? (hi - (j - 1)) : j;
        if (BWD) { if (rw < 0) rw = 0; } else { if (rw > nsteps) rw = nsteps; }
        aload3(p0 + (size_t)rw * (size_t)estride, r[d][0], r[d][1], r[d][2]);
    };
#pragma unroll
    for (int d = 0; d < DEPTH; ++d) issue(d, 1 + d);

    int j = 1;
    for (;;) {
#pragma unroll
        for (int d = 0; d < DEPTH; ++d) {
            WAITVM(3 * (DEPTH - 1));  // oldest 3 loads (slot d) have landed
            float4 e0 = r[d][0], e1 = r[d][1], e2 = r[d][2];
            if (!BWD) {
                DO_MFMA6();
                EMMUL(e0, e1, e2);
                if (j == nsteps) goto done;
                if ((j & (RP - 1)) == 0) RESCALE(Cexp);
                REPACK_B();
            } else {
                EMMUL(e0, e1, e2);
                REPACK_B();
                DO_MFMA6();
                if (j == nsteps) goto done;
                if ((j & (RP - 1)) == 0) RESCALE(Cexp);
            }
            issue(d, j + DEPTH);
            ++j;
        }
    }
done:
    WAITVM(0);  // drain ring: slots' vregs may be reused by later code
}

__device__ __forceinline__ void initB(const float* __restrict__ p0, s8v& B0, s8v& B1) {
    float4 ua = *(const float4*)(p0);
    float4 ub = *(const float4*)(p0 + 16);
    float4 uc = *(const float4*)(p0 + 32);
    i4v b0i = {pk_bf16(__expf(ua.x), __expf(ua.y)), pk_bf16(__expf(ua.z), __expf(ua.w)),
               pk_bf16(__expf(ub.x), __expf(ub.y)), pk_bf16(__expf(ub.z), __expf(ub.w))};
    i4v b1i = {pk_bf16(__expf(uc.x), __expf(uc.y)), pk_bf16(__expf(uc.z), __expf(uc.w)), 0, 0};
    B0 = __builtin_bit_cast(s8v, b0i);
    B1 = __builtin_bit_cast(s8v, b1i);
}

// L/R denominator: fwd chain + final logsum.
template <int RP, int DEPTH>
__device__ __forceinline__ float den16a(const float* __restrict__ p0, int estride,
                                        int steps, const s8v (&A)[3][2]) {
    const f4 Zi = {0.f, 0.f, 0.f, 0.f};
    f4 D0 = Zi, D1 = Zi, D2 = Zi;
    s8v B0, B1;
    int Cexp = 0;
    initB(p0, B0, B1);
    chain<RP, DEPTH, false>(p0, estride, steps, 0, A, B0, B1, D0, D1, D2, Cexp);
    float S = ((D0[0] + D0[1]) + (D0[2] + D0[3])) +
              ((D1[0] + D1[1]) + (D1[2] + D1[3])) +
              ((D2[0] + D2[1]) + (D2[2] + D2[3]));
    S += __shfl_xor(S, 16, 64);
    S += __shfl_xor(S, 32, 64);
    return __logf(S) + (float)Cexp * LN2;
}

__device__ __forceinline__ float den0(const float* __restrict__ p0) {
    float4 ua = *(const float4*)(p0);
    float4 ub = *(const float4*)(p0 + 16);
    float4 uc = *(const float4*)(p0 + 32);
    float S = (__expf(ua.x) + __expf(ua.y) + __expf(ua.z) + __expf(ua.w)) +
              (__expf(ub.x) + __expf(ub.y) + __expf(ub.z) + __expf(ub.w)) +
              (__expf(uc.x) + __expf(uc.y) + __expf(uc.z) + __expf(uc.w));
    S += __shfl_xor(S, 16, 64);
    S += __shfl_xor(S, 32, 64);
    return __logf(S);
}

// A-frags fwd: A[m][k] = exp(trans[σ(k)][t*16+m])  (Eᵀ·u)
__device__ __forceinline__ void build_A_fwd(const float* __restrict__ st, s8v (&A)[3][2]) {
    int lane = threadIdx.x & 63, m = lane & 15, quad = lane >> 4;
#pragma unroll
    for (int t = 0; t < 3; ++t) {
        int col = t * 16 + m;
        i4v v0 = {pk_bf16(__expf(st[(quad * 4 + 0) * NN + col]), __expf(st[(quad * 4 + 1) * NN + col])),
                  pk_bf16(__expf(st[(quad * 4 + 2) * NN + col]), __expf(st[(quad * 4 + 3) * NN + col])),
                  pk_bf16(__expf(st[(16 + quad * 4 + 0) * NN + col]), __expf(st[(16 + quad * 4 + 1) * NN + col])),
                  pk_bf16(__expf(st[(16 + quad * 4 + 2) * NN + col]), __expf(st[(16 + quad * 4 + 3) * NN + col]))};
        i4v v1 = {pk_bf16(__expf(st[(32 + quad * 4 + 0) * NN + col]), __expf(st[(32 + quad * 4 + 1) * NN + col])),
                  pk_bf16(__expf(st[(32 + quad * 4 + 2) * NN + col]), __expf(st[(32 + quad * 4 + 3) * NN + col])),
                  0, 0};
        A[t][0] = __builtin_bit_cast(s8v, v0);
        A[t][1] = __builtin_bit_cast(s8v, v1);
    }
}

// A-frags bwd: A[m][k] = exp(trans[t*16+m][σ(k)])  (E·x)
__device__ __forceinline__ void build_A_bwd(const float* __restrict__ st, s8v (&A)[3][2]) {
    int lane = threadIdx.x & 63, m = lane & 15, quad = lane >> 4;
#pragma unroll
    for (int t = 0; t < 3; ++t) {
        const float* row = st + (t * 16 + m) * NN;
        i4v v0 = {pk_bf16(__expf(row[quad * 4 + 0]), __expf(row[quad * 4 + 1])),
                  pk_bf16(__expf(row[quad * 4 + 2]), __expf(row[quad * 4 + 3])),
                  pk_bf16(__expf(row[16 + quad * 4 + 0]), __expf(row[16 + quad * 4 + 1])),
                  pk_bf16(__expf(row[16 + quad * 4 + 2]), __expf(row[16 + quad * 4 + 3]))};
        i4v v1 = {pk_bf16(__expf(row[32 + quad * 4 + 0]), __expf(row[32 + quad * 4 + 1])),
                  pk_bf16(__expf(row[32 + quad * 4 + 2]), __expf(row[32 + quad * 4 + 3])),
                  0, 0};
        A[t][0] = __builtin_bit_cast(s8v, v0);
        A[t][1] = __builtin_bit_cast(s8v, v1);
    }
}

__device__ __forceinline__ void dumpD(float* __restrict__ dst, int* __restrict__ cdst,
                                      int g, f4 D0, f4 D1, f4 D2, int Cexp) {
    int lane = threadIdx.x & 63, seq = lane & 15, quad = lane >> 4;
    float* b = dst + (size_t)(g * 16 + seq) * 48 + quad * 4;
#pragma unroll
    for (int r = 0; r < 4; ++r) {
        b[0 * 16 + r] = D0[r];
        b[1 * 16 + r] = D1[r];
        b[2 * 16 + r] = D2[r];
    }
    if (quad == 0) cdst[g * 16 + seq] = Cexp;
}

__global__ void zero_out(float* out) {
    if (threadIdx.x < 3) out[threadIdx.x] = 0.f;
}

#define WS_BETA (64 * 16 * 48)
#define WS_C (2 * 64 * 16 * 48)

// ---------------------------------------------------------------------------
// crf_fused: 4480 blocks x 64 thr. bid<128: pyramid-T halves (longest waves,
// dispatched first); else LR work. Fusion overlaps the latency-bound halves.
// ROUND-21 THEORY: dur == FETCH/1.84 TB/s — the kernel rides its memory phase.
// R re-reads the same logits rows L reads (R(tb) ⊂ L(tb)∪L(tb+1)), but the
// old dispatch put L and R ~2000 bids apart so R missed cache. This round:
// L/R blocks INTERLEAVED (even lb = L(i), odd lb = R(i), i = lb>>1) so R's
// reads hit L2/L3 lines L just fetched. Pure index bijection — same work,
// same numerics (atomic order may reassociate; threshold is 4.5e4).
// Probed and rejected: pack variants (NaN/abort, r6/r8), paired-drain+setprio
// (+18%, r11), DEPTH 12/16 (ring spill → abort, r16/r20).
// __launch_bounds__(64,1): full 512-VGPR budget — REQUIRED (spill ops bump
// vmcnt and corrupt the asm-ring accounting; (64,3) caused the round-3 abort).
// ---------------------------------------------------------------------------
__global__ __launch_bounds__(64, 1) void crf_fused(const float* __restrict__ logits,
                                                   const float* __restrict__ transT,
                                                   const float* __restrict__ transL,
                                                   const float* __restrict__ transR,
                                                   const int* __restrict__ tags,
                                                   float* __restrict__ out,
                                                   float* __restrict__ ws) {
    __shared__ float st[NN * NN];
    const int tid = threadIdx.x, bid = blockIdx.x;
    const int lane = tid & 63;
    const int quad = lane >> 4, seq = lane & 15;
    const int SPN = BB * TT * NN;

    if (bid < 128) {
        // ---- former crf_T: pyramid-T chains, fwd half (dir=0) / bwd half ----
        for (int i = tid; i < NN * NN; i += 64) st[i] = transT[i];
        __syncthreads();

        const int dir = bid >> 6, g = bid & 63;
        const int p = g >> 2, b0 = (g & 3) * 16;
        const int steps = (TT - 1) - p;
        const int m = steps >> 1, nb = steps - m;
        const float* p0 = logits + (size_t)(p * BB + b0 + seq) * (TT * NN) + quad * 4;

        s8v A[3][2];
        const f4 Zi = {0.f, 0.f, 0.f, 0.f};
        f4 D0 = Zi, D1 = Zi, D2 = Zi;
        s8v B0, B1;
        int Cexp = 0;
        int* cf = (int*)(ws + WS_C);
        if (dir == 0) {
            build_A_fwd(st, A);
            initB(p0, B0, B1);
            chain<4, 8, false>(p0, NN, m, 0, A, B0, B1, D0, D1, D2, Cexp);
            dumpD(ws, cf, g, D0, D1, D2, Cexp);
        } else {
            build_A_bwd(st, A);
            D0 = f4{1.f, 1.f, 1.f, 1.f}; D1 = D0; D2 = D0;
            chain<4, 8, true>(p0, NN, nb, steps, A, B0, B1, D0, D1, D2, Cexp);
            dumpD(ws + WS_BETA, cf + 1024, g, D0, D1, D2, Cexp);
        }
        return;
    }

    // ---- former crf_LR ----
    const int lb = bid - 128;

    // L/R interleave: even lb → L(i), odd lb → R(i), i = lb>>1 (bijective over
    // the original 2×1984 uniform blocks; tails and T-numerator unchanged).
    const int uniIsL = (lb & 1) == 0;
    const int uniI = lb >> 1;

    const float* tr;
    if (lb < 3968) tr = uniIsL ? transL : transR;
    else if (lb < 4032) tr = transL;
    else if (lb < 4096) tr = transR;
    else tr = transT;
    for (int i = tid; i < NN * NN; i += 64) st[i] = tr[i];
    __syncthreads();

    float contrib = 0.f;
    int oi;
    if (lb < 3968) {
        const int isL = uniIsL;
        const int i = uniI;
        const int tb = i >> 6, b = i & 63;
        const int t0 = (isL ? 0 : 16) + tb * 16;
        oi = isL ? 1 : 2;
        const int estride = isL ? SPN : SPN - NN;
        s8v A[3][2];
        build_A_fwd(st, A);
        const float* p0 = logits + (size_t)(b * TT + t0 + seq) * NN + quad * 4;
        float ld = den16a<8, 5>(p0, estride, PP - 1, A);
        int sq = lane >> 2, pc = lane & 3;
        int tq = t0 + sq;
        float sc = 0.f;
        if (isL) {
            for (int p2 = pc; p2 < PP; p2 += 4) {
                int ix = (p2 * BB + b) * TT + tq;
                int tg = tags[ix];
                sc += logits[(size_t)ix * NN + tg];
                if (p2 >= 1) sc += st[tags[ix - BB * TT] * NN + tg];
            }
        } else {
            for (int p2 = pc; p2 < PP; p2 += 4) {
                int ix = (p2 * BB + b) * TT + (tq - p2);
                int tg = tags[ix];
                sc += logits[(size_t)ix * NN + tg];
                if (p2 >= 1) sc += st[tags[ix - BB * TT + 1] * NN + tg];
            }
        }
        contrib = ((quad == 0) ? ld : 0.f) - sc;
    } else if (lb < 4096) {
        const int isL = lb < 4032;
        const int i = isL ? lb - 3968 : lb - 4032;
        const int t = isL ? 496 + (i >> 2) : (i >> 2);
        const int b0 = (i & 3) * 16;
        oi = isL ? 1 : 2;
        const int Lh = isL ? (TT - t) : (t + 1);
        const int steps = Lh - 1;
        const int estride = isL ? SPN : SPN - NN;
        s8v A[3][2];
        build_A_fwd(st, A);
        const float* p0 = logits + (size_t)(b0 + seq) * (TT * NN) + t * NN + quad * 4;
        float ld = (steps > 0) ? den16a<8, 5>(p0, estride, steps, A) : den0(p0);
        float sc = 0.f;
        int sq = lane >> 2, pc = lane & 3;
        int bq = b0 + sq;
        if (isL) {
            for (int p2 = pc; p2 < Lh; p2 += 4) {
                int ix = (p2 * BB + bq) * TT + t;
                int tg = tags[ix];
                sc += logits[(size_t)ix * NN + tg];
                if (p2 >= 1) sc += st[tags[ix - BB * TT] * NN + tg];
            }
        } else {
            for (int p2 = pc; p2 < Lh; p2 += 4) {
                int ix = (p2 * BB + bq) * TT + (t - p2);
                int tg = tags[ix];
                sc += logits[(size_t)ix * NN + tg];
                if (p2 >= 1) sc += st[tags[ix - BB * TT + 1] * NN + tg];
            }
        }
        contrib = ((quad == 0) ? ld : 0.f) - sc;
    } else {
        oi = 0;
        int q = lb - 4096;
        int g = q >> 2, phase = q & 3;
        int p = g >> 2, b0 = (g & 3) * 16;
        int Ls = TT - p;
        int sq = lane >> 2;
        int t0 = phase * 4 + (lane & 3);
        const float* lgs = logits + (size_t)(p * BB + b0 + sq) * (TT * NN);
        const int* tgs = tags + (size_t)(p * BB + b0 + sq) * TT;
        float sc = 0.f;
        for (int t = t0; t < Ls; t += 16) {
            int tg = tgs[t];
            float e = lgs[t * NN + tg];
            float tsc = (t >= 1) ? st[tgs[t - 1] * NN + tg] : 0.f;
            sc += e + tsc;
        }
        contrib = -sc;
    }

    contrib = wsum(contrib);
    if (lane == 0) atomicAdd(&out[oi], contrib);
}

// Combine T halves: out[0] += Σ_idx [ log(Σ_s alpha*beta) + ln2*(cf+cb) ]
__global__ __launch_bounds__(256) void t_combine(const float* __restrict__ ws,
                                                 float* __restrict__ out) {
    const int idx = blockIdx.x * 256 + threadIdx.x;  // 0..1023
    const float* ap = ws + (size_t)idx * 48;
    const float* bp = ws + WS_BETA + (size_t)idx * 48;
    const int* cf = (const int*)(ws + WS_C);
    const int* cb = cf + 1024;
    float Zv = 0.f;
#pragma unroll
    for (int s = 0; s < 48; ++s) Zv += ap[s] * bp[s];
    float acc = __logf(Zv) + LN2 * (float)(cf[idx] + cb[idx]);
    acc = wsum(acc);
    if ((threadIdx.x & 63) == 0) atomicAdd(&out[0], acc);
}

extern "C" void kernel_launch(void* const* d_in, const int* in_sizes, int n_in,
                              void* d_out, int out_size, void* d_ws, size_t ws_size,
                              hipStream_t stream) {
    const float* logits = (const float*)d_in[0];
    const float* trans_T = (const float*)d_in[1];
    const float* trans_L = (const float*)d_in[2];
    const float* trans_R = (const float*)d_in[3];
    const int* tags = (const int*)d_in[4];
    float* out = (float*)d_out;
    float* ws = (float*)d_ws;

    hipLaunchKernelGGL(zero_out, dim3(1), dim3(64), 0, stream, out);
    hipLaunchKernelGGL(crf_fused, dim3(4480), dim3(64), 0, stream,
                       logits, trans_T, trans_L, trans_R, tags, out, ws);
    hipLaunchKernelGGL(t_combine, dim3(4), dim3(256), 0, stream, ws, out);
}